// Round 6
// baseline (326.742 us; speedup 1.0000x reference)
//
#include <hip/hip_runtime.h>

// Problem constants (from the reference)
namespace {
constexpr int N_MODELS = 64;
constexpr int N_RECV   = 32;
constexpr int NXg = 64, NYg = 64;
constexpr int NTI = 614;            // N_T_INT = int(512 * 24/20)
constexpr int NTO = 512;            // N_T
constexpr int NU  = NTI - 4;        // 610 interior Thomas unknowns (m_2..m_611)
constexpr double H_INT_D = 24.0 / 613.0;   // (TN+MAX_SHIFT - T0_INT)/(N_T_INT-1)
constexpr double DX_D    = 2.0 / 63.0;     // (GRID_MAX-GRID_MIN)/(NX-1)
}

// One block per (model, receiver) pair. 256 threads.
// LDS: y[3][614] + m[3][614] + invb[610] ~= 16.8 KB -> 8 blocks/CU, 32 waves/CU.
__global__ __launch_bounds__(256)
void fused_seis_kernel(const float* __restrict__ ms,   // (64, 9)
                       const float* __restrict__ rc,   // (32, 2)
                       const float* __restrict__ tab,  // (64, 64, 3, 614, 6)
                       float* __restrict__ out)        // (64, 32, 3, 512)
{
  __shared__ float y_s[3][NTI];
  __shared__ float m_s[3][NTI];
  __shared__ float invb[NU];

  const int tid  = threadIdx.x;
  const int pair = blockIdx.x;
  const int mi   = pair >> 5;            // / N_RECV
  const int ri   = pair & (N_RECV - 1);

  // ---------------- uniform scalar setup ----------------
  const float hx  = ms[mi*9 + 0] - rc[ri*2 + 0];
  const float hy  = ms[mi*9 + 1] - rc[ri*2 + 1];
  const float tsh = ms[mi*9 + 2];
  float mt[6];
#pragma unroll
  for (int j = 0; j < 6; ++j) mt[j] = ms[mi*9 + 3 + j];

  const float dxf = (float)DX_D;
  const float uu = (hx + 1.0f) / dxf;    // (x - GRID_MIN)/dx
  const float vv = (hy + 1.0f) / dxf;
  int i0 = (int)floorf(uu); i0 = min(max(i0, 0), NXg - 2);
  int j0 = (int)floorf(vv); j0 = min(max(j0, 0), NYg - 2);
  const float fu = uu - (float)i0;
  const float fv = vv - (float)j0;
  const float w00 = (1.f - fu) * (1.f - fv);
  const float w10 = fu * (1.f - fv);
  const float w01 = (1.f - fu) * fv;
  const float w11 = fu * fv;

  const size_t cellf = (size_t)3 * NTI * 6;     // floats per (i,j) cell (11052, /4 -> f4-aligned)
  const float4* c00 = (const float4*)(tab + (size_t)( i0      * NYg + j0    ) * cellf);
  const float4* c10 = (const float4*)(tab + (size_t)((i0 + 1) * NYg + j0    ) * cellf);
  const float4* c01 = (const float4*)(tab + (size_t)( i0      * NYg + j0 + 1) * cellf);
  const float4* c11 = (const float4*)(tab + (size_t)((i0 + 1) * NYg + j0 + 1) * cellf);

  // ---------------- invb table for constant-coefficient Thomas ----------------
  // invb[p] = 1/(4 - invb[p-1]); converges to 2-sqrt(3) in <24 steps (double-precision exact).
  if (tid == 0) {
    double c = 0.0;
#pragma unroll
    for (int p = 0; p < 24; ++p) { c = 1.0 / (4.0 - c); invb[p] = (float)c; }
  }
  for (int p = 24 + tid; p < NU; p += 256) invb[p] = 0.26794919243112270f; // 2 - sqrt(3)

  // ---------------- phase A: y[k][t] = sum_c w_c * dot(mt, table_c[k,t,:]) -------------
  // Two adjacent t's = 12 contiguous floats = 3 aligned float4 per cell (NTI even).
#pragma unroll
  for (int k = 0; k < 3; ++k) {
    for (int tp = tid; tp < NTI / 2; tp += 256) {
      const int o4 = (k * (NTI / 2) + tp) * 3;     // float4 index of the 12-float pair
      const int t0 = 2 * tp;
      float d0a = 0.f, d0b = 0.f;                  // accumulators for t0, t0+1
      {
        const float4 q0 = c00[o4], q1 = c00[o4+1], q2 = c00[o4+2];
        d0a += w00 * (mt[0]*q0.x + mt[1]*q0.y + mt[2]*q0.z + mt[3]*q0.w + mt[4]*q1.x + mt[5]*q1.y);
        d0b += w00 * (mt[0]*q1.z + mt[1]*q1.w + mt[2]*q2.x + mt[3]*q2.y + mt[4]*q2.z + mt[5]*q2.w);
      }
      {
        const float4 q0 = c10[o4], q1 = c10[o4+1], q2 = c10[o4+2];
        d0a += w10 * (mt[0]*q0.x + mt[1]*q0.y + mt[2]*q0.z + mt[3]*q0.w + mt[4]*q1.x + mt[5]*q1.y);
        d0b += w10 * (mt[0]*q1.z + mt[1]*q1.w + mt[2]*q2.x + mt[3]*q2.y + mt[4]*q2.z + mt[5]*q2.w);
      }
      {
        const float4 q0 = c01[o4], q1 = c01[o4+1], q2 = c01[o4+2];
        d0a += w01 * (mt[0]*q0.x + mt[1]*q0.y + mt[2]*q0.z + mt[3]*q0.w + mt[4]*q1.x + mt[5]*q1.y);
        d0b += w01 * (mt[0]*q1.z + mt[1]*q1.w + mt[2]*q2.x + mt[3]*q2.y + mt[4]*q2.z + mt[5]*q2.w);
      }
      {
        const float4 q0 = c11[o4], q1 = c11[o4+1], q2 = c11[o4+2];
        d0a += w11 * (mt[0]*q0.x + mt[1]*q0.y + mt[2]*q0.z + mt[3]*q0.w + mt[4]*q1.x + mt[5]*q1.y);
        d0b += w11 * (mt[0]*q1.z + mt[1]*q1.w + mt[2]*q2.x + mt[3]*q2.y + mt[4]*q2.z + mt[5]*q2.w);
      }
      y_s[k][t0]     = d0a;
      y_s[k][t0 + 1] = d0b;
    }
  }
  __syncthreads();

  // ---------------- phase A2: rhs_i = 6*(y[i-1]-2y[i]+y[i+1])/H^2 into m_s[k][1..612] ----
  const float hh = (float)(H_INT_D * H_INT_D);
#pragma unroll
  for (int k = 0; k < 3; ++k) {
    for (int t = tid; t < NTI - 2; t += 256) {
      const int i = t + 1;
      m_s[k][i] = 6.0f * (y_s[k][i-1] - 2.0f * y_s[k][i] + y_s[k][i+1]) / hh;
    }
  }
  __syncthreads();

  // ---------------- phase B: spline solve (3 SIMT lanes, one per component k) ----------
  // Row 0:   m0 - 2m1 + m2 = 0      with row 1   ->  6*m1   = rhs_1
  // Row n-1: m611 - 2m612 + m613 = 0 with row n-2 -> 6*m612 = rhs_612
  // Interior m_2..m_611: [1,4,1] tridiagonal -> Thomas with precomputed invb.
  if (tid < 3) {
    const int k = tid;
    const float m1   = m_s[k][1]   / 6.0f;
    const float m612 = m_s[k][612] / 6.0f;

    float dprev = 0.0f;
    for (int p = 0; p < NU; ++p) {
      float r = m_s[k][2 + p];
      if (p == 0)      r -= m1;
      if (p == NU - 1) r -= m612;
      const float dp = (r - dprev) * invb[p];
      m_s[k][2 + p] = dp;        // store d'
      dprev = dp;
    }
    float xn = dprev;            // x_{NU-1} = d'_{NU-1}
    for (int p = NU - 2; p >= 0; --p) {
      xn = m_s[k][2 + p] - invb[p] * xn;   // in-place back-substitution
      m_s[k][2 + p] = xn;
    }
    m_s[k][1]   = m1;
    m_s[k][612] = m612;
    m_s[k][0]   = 2.0f * m1   - m_s[k][2];
    m_s[k][613] = 2.0f * m612 - m_s[k][611];
  }
  __syncthreads();

  // ---------------- phase C: cubic sample at t_out - tshift ----------------
  const float Hf   = (float)H_INT_D;
  const float h26  = (float)(H_INT_D * H_INT_D / 6.0);
  const float tstep = (float)(20.0 / 511.0);
  float* outp = out + ((size_t)(mi * N_RECV + ri) * 3) * NTO;
  for (int t = tid; t < NTO; t += 256) {
    const float tout = (float)t * tstep;
    const float tq   = tout - tsh;
    const float uq   = (tq + 2.0f) / Hf;       // (tq - T0_INT)/H_INT
    int idx = (int)floorf(uq);
    idx = min(max(idx, 0), NTI - 2);
    const float a  = (float)(idx + 1) - uq;
    const float b  = uq - (float)idx;
    const float a3 = a*a*a - a;
    const float b3 = b*b*b - b;
#pragma unroll
    for (int k = 0; k < 3; ++k) {
      const float val = a * y_s[k][idx] + b * y_s[k][idx + 1]
                      + (a3 * m_s[k][idx] + b3 * m_s[k][idx + 1]) * h26;
      outp[(size_t)k * NTO + t] = val;
    }
  }
}

extern "C" void kernel_launch(void* const* d_in, const int* in_sizes, int n_in,
                              void* d_out, int out_size, void* d_ws, size_t ws_size,
                              hipStream_t stream) {
  const float* ms  = (const float*)d_in[0];   // model_samples (64,9)
  const float* rc  = (const float*)d_in[1];   // receivers (32,2)
  const float* tab = (const float*)d_in[2];   // lookup_table (64,64,3,614,6)
  float* out = (float*)d_out;                 // (64,32,3,512) f32

  fused_seis_kernel<<<dim3(N_MODELS * N_RECV), dim3(256), 0, stream>>>(ms, rc, tab, out);
}

// Round 7
// 280.177 us; speedup vs baseline: 1.1662x; 1.1662x over previous
//
#include <hip/hip_runtime.h>

// Problem constants (from the reference)
namespace {
constexpr int N_MODELS = 64;
constexpr int N_RECV   = 32;
constexpr int NXg = 64, NYg = 64;
constexpr int NTI = 614;            // N_T_INT
constexpr int NTO = 512;            // N_T
constexpr int NU  = NTI - 4;        // 610 interior unknowns (m_2..m_611)
constexpr int W   = 16;             // truncated-inverse window; r^17 ~ 2e-10
constexpr double H_INT_D = 24.0 / 613.0;
constexpr double DX_D    = 2.0 / 63.0;

// Ks[a] = (-1)^a * (2-sqrt(3))^a / (2*sqrt(3)) — signed inverse-kernel taps
__device__ __constant__ float Ks[W + 1] = {
   0.2886751345948129f,  -0.0773502691896258f,   0.0207257033081726f,
  -0.0055534135887359f,   0.0014880108762223f,  -0.0003987097583156f,
   0.0001068340364620f,  -0.0000286260504370f,   0.0000076703256763f,
  -0.0000020552580728f,   0.0000005507044461f,  -0.0000001475608686f,
   0.0000000395388899f,  -0.0000000105944428f,   0.0000000028387720f,
  -0.0000000007606466f,   0.0000000002038148f
};
}

// One block per (model, receiver) pair. 256 threads.
// LDS: y[3][614] + m[3][614] = 14.4 KB -> 8 blocks/CU (wave-cap), 32 waves/CU.
__global__ __launch_bounds__(256)
void fused_seis_kernel(const float* __restrict__ ms,   // (64, 9)
                       const float* __restrict__ rc,   // (32, 2)
                       const float* __restrict__ tab,  // (64, 64, 3, 614, 6)
                       float* __restrict__ out)        // (64, 32, 3, 512)
{
  __shared__ float y_s[3][NTI];
  __shared__ float m_s[3][NTI];

  const int tid  = threadIdx.x;
  // XCD-aware swizzle (T1): round-robin dispatch puts blockIdx%8 on XCD k;
  // remap so each XCD gets 256 consecutive pairs = 8 whole models (cells
  // shared by a model's 32 receivers then live in ONE per-XCD L2).
  const int pair = (blockIdx.x & 7) * 256 + (blockIdx.x >> 3);
  const int mi   = pair >> 5;            // / N_RECV
  const int ri   = pair & (N_RECV - 1);

  // ---------------- uniform scalar setup ----------------
  const float hx  = ms[mi*9 + 0] - rc[ri*2 + 0];
  const float hy  = ms[mi*9 + 1] - rc[ri*2 + 1];
  const float tsh = ms[mi*9 + 2];
  float mt[6];
#pragma unroll
  for (int j = 0; j < 6; ++j) mt[j] = ms[mi*9 + 3 + j];

  const float dxf = (float)DX_D;
  const float uu = (hx + 1.0f) / dxf;
  const float vv = (hy + 1.0f) / dxf;
  int i0 = (int)floorf(uu); i0 = min(max(i0, 0), NXg - 2);
  int j0 = (int)floorf(vv); j0 = min(max(j0, 0), NYg - 2);
  const float fu = uu - (float)i0;
  const float fv = vv - (float)j0;
  const float w00 = (1.f - fu) * (1.f - fv);
  const float w10 = fu * (1.f - fv);
  const float w01 = (1.f - fu) * fv;
  const float w11 = fu * fv;

  const size_t cellf = (size_t)3 * NTI * 6;     // 11052 floats per cell (16B-aligned)
  const float4* c00 = (const float4*)(tab + (size_t)( i0      * NYg + j0    ) * cellf);
  const float4* c10 = (const float4*)(tab + (size_t)((i0 + 1) * NYg + j0    ) * cellf);
  const float4* c01 = (const float4*)(tab + (size_t)( i0      * NYg + j0 + 1) * cellf);
  const float4* c11 = (const float4*)(tab + (size_t)((i0 + 1) * NYg + j0 + 1) * cellf);

  // ---------------- phase A: y[k][t] = sum_c w_c * dot(mt, table_c[k,t,:]) -------------
#pragma unroll
  for (int k = 0; k < 3; ++k) {
    for (int tp = tid; tp < NTI / 2; tp += 256) {
      const int o4 = (k * (NTI / 2) + tp) * 3;
      const int t0 = 2 * tp;
      float d0a = 0.f, d0b = 0.f;
      {
        const float4 q0 = c00[o4], q1 = c00[o4+1], q2 = c00[o4+2];
        d0a += w00 * (mt[0]*q0.x + mt[1]*q0.y + mt[2]*q0.z + mt[3]*q0.w + mt[4]*q1.x + mt[5]*q1.y);
        d0b += w00 * (mt[0]*q1.z + mt[1]*q1.w + mt[2]*q2.x + mt[3]*q2.y + mt[4]*q2.z + mt[5]*q2.w);
      }
      {
        const float4 q0 = c10[o4], q1 = c10[o4+1], q2 = c10[o4+2];
        d0a += w10 * (mt[0]*q0.x + mt[1]*q0.y + mt[2]*q0.z + mt[3]*q0.w + mt[4]*q1.x + mt[5]*q1.y);
        d0b += w10 * (mt[0]*q1.z + mt[1]*q1.w + mt[2]*q2.x + mt[3]*q2.y + mt[4]*q2.z + mt[5]*q2.w);
      }
      {
        const float4 q0 = c01[o4], q1 = c01[o4+1], q2 = c01[o4+2];
        d0a += w01 * (mt[0]*q0.x + mt[1]*q0.y + mt[2]*q0.z + mt[3]*q0.w + mt[4]*q1.x + mt[5]*q1.y);
        d0b += w01 * (mt[0]*q1.z + mt[1]*q1.w + mt[2]*q2.x + mt[3]*q2.y + mt[4]*q2.z + mt[5]*q2.w);
      }
      {
        const float4 q0 = c11[o4], q1 = c11[o4+1], q2 = c11[o4+2];
        d0a += w11 * (mt[0]*q0.x + mt[1]*q0.y + mt[2]*q0.z + mt[3]*q0.w + mt[4]*q1.x + mt[5]*q1.y);
        d0b += w11 * (mt[0]*q1.z + mt[1]*q1.w + mt[2]*q2.x + mt[3]*q2.y + mt[4]*q2.z + mt[5]*q2.w);
      }
      y_s[k][t0]     = d0a;
      y_s[k][t0 + 1] = d0b;
    }
  }
  __syncthreads();

  // ---------------- phase A2: rhs_i = 6*(y[i-1]-2y[i]+y[i+1])/H^2 into m_s[k][1..612] ----
  const float hh = (float)(H_INT_D * H_INT_D);
#pragma unroll
  for (int k = 0; k < 3; ++k) {
    for (int t = tid; t < NTI - 2; t += 256) {
      const int i = t + 1;
      m_s[k][i] = 6.0f * (y_s[k][i-1] - 2.0f * y_s[k][i] + y_s[k][i+1]) / hh;
    }
  }
  __syncthreads();

  // ---------------- phase B0: boundary elimination (NAK rows) -----------------------
  // 6*m1 = rhs_1 ; 6*m612 = rhs_612 ; fold into neighbors' rhs (b_0 -= m1, b_609 -= m612).
  if (tid < 6) {
    const int k = tid >> 1;
    if ((tid & 1) == 0) {
      const float m1 = m_s[k][1] * (1.0f / 6.0f);
      m_s[k][1]  = m1;
      m_s[k][2] -= m1;
    } else {
      const float m612 = m_s[k][612] * (1.0f / 6.0f);
      m_s[k][612]  = m612;
      m_s[k][611] -= m612;
    }
  }
  __syncthreads();

  // ---------------- phase B1: parallel truncated-inverse solve ----------------------
  // Interior system: tridiag(1,4,1), n=610, b_j = m_s[k][2+j].
  // x_i = sum_{|d|<=W} Ks[|d|] b_{i+d}  -  image_left  -  image_right
  // (odd-reflection images enforce the eliminated ghost zeros x_{-1}=x_n=0).
  float xreg[8];
  int   nq = 0;
  for (int q = tid; q < 3 * NU; q += 256, ++nq) {
    const int k = (q >= 2*NU) ? 2 : (q >= NU ? 1 : 0);
    const int i = q - k * NU;
    const float* b = &m_s[k][2];
    float acc = 0.0f;
#pragma unroll
    for (int d = -W; d <= W; ++d) {
      const int j = i + d;
      if (j >= 0 && j < NU) acc += Ks[d < 0 ? -d : d] * b[j];
    }
    if (i <= W - 2) {                 // left image
      for (int j = 0; j <= W - 2 - i; ++j) acc -= Ks[i + j + 2] * b[j];
    }
    const int ip = (NU - 1) - i;
    if (ip <= W - 2) {                // right image (mirrored)
      for (int jp = 0; jp <= W - 2 - ip; ++jp) acc -= Ks[ip + jp + 2] * b[(NU - 1) - jp];
    }
    xreg[nq] = acc;
  }
  __syncthreads();
  nq = 0;
  for (int q = tid; q < 3 * NU; q += 256, ++nq) {
    const int k = (q >= 2*NU) ? 2 : (q >= NU ? 1 : 0);
    const int i = q - k * NU;
    m_s[k][2 + i] = xreg[nq];
  }
  __syncthreads();
  if (tid < 6) {                      // endpoints: m0 = 2m1 - m2, m613 = 2m612 - m611
    const int k = tid >> 1;
    if ((tid & 1) == 0) m_s[k][0]   = 2.0f * m_s[k][1]   - m_s[k][2];
    else                m_s[k][613] = 2.0f * m_s[k][612] - m_s[k][611];
  }
  __syncthreads();

  // ---------------- phase C: cubic sample at t_out - tshift ----------------
  const float Hf   = (float)H_INT_D;
  const float h26  = (float)(H_INT_D * H_INT_D / 6.0);
  const float tstep = (float)(20.0 / 511.0);
  float* outp = out + ((size_t)(mi * N_RECV + ri) * 3) * NTO;
  for (int t = tid; t < NTO; t += 256) {
    const float tout = (float)t * tstep;
    const float tq   = tout - tsh;
    const float uq   = (tq + 2.0f) / Hf;
    int idx = (int)floorf(uq);
    idx = min(max(idx, 0), NTI - 2);
    const float a  = (float)(idx + 1) - uq;
    const float b  = uq - (float)idx;
    const float a3 = a*a*a - a;
    const float b3 = b*b*b - b;
#pragma unroll
    for (int k = 0; k < 3; ++k) {
      const float val = a * y_s[k][idx] + b * y_s[k][idx + 1]
                      + (a3 * m_s[k][idx] + b3 * m_s[k][idx + 1]) * h26;
      outp[(size_t)k * NTO + t] = val;
    }
  }
}

extern "C" void kernel_launch(void* const* d_in, const int* in_sizes, int n_in,
                              void* d_out, int out_size, void* d_ws, size_t ws_size,
                              hipStream_t stream) {
  const float* ms  = (const float*)d_in[0];   // model_samples (64,9)
  const float* rc  = (const float*)d_in[1];   // receivers (32,2)
  const float* tab = (const float*)d_in[2];   // lookup_table (64,64,3,614,6)
  float* out = (float*)d_out;                 // (64,32,3,512) f32

  fused_seis_kernel<<<dim3(N_MODELS * N_RECV), dim3(256), 0, stream>>>(ms, rc, tab, out);
}

// Round 8
// 264.730 us; speedup vs baseline: 1.2342x; 1.0584x over previous
//
#include <hip/hip_runtime.h>

// Problem constants (from the reference)
namespace {
constexpr int N_MODELS = 64;
constexpr int N_RECV   = 32;
constexpr int NXg = 64, NYg = 64;
constexpr int NTI = 614;            // N_T_INT
constexpr int NTO = 512;            // N_T
constexpr int NU  = NTI - 4;        // 610 interior unknowns (m_2..m_611)
constexpr int W   = 16;             // truncated-inverse window; r^17 ~ 2e-10
constexpr double H_INT_D = 24.0 / 613.0;
constexpr double DX_D    = 2.0 / 63.0;

// Ks[a] = (-1)^a * (2-sqrt(3))^a / (2*sqrt(3)) — signed inverse-kernel taps
__device__ __constant__ float Ks[W + 1] = {
   0.2886751345948129f,  -0.0773502691896258f,   0.0207257033081726f,
  -0.0055534135887359f,   0.0014880108762223f,  -0.0003987097583156f,
   0.0001068340364620f,  -0.0000286260504370f,   0.0000076703256763f,
  -0.0000020552580728f,   0.0000005507044461f,  -0.0000001475608686f,
   0.0000000395388899f,  -0.0000000105944428f,   0.0000000028387720f,
  -0.0000000007606466f,   0.0000000002038148f
};
}

// One block per (model, receiver, component). 256 threads.
// LDS: y[614] + m[614] = 4.9 KB. 8 blocks/CU resident (wave-cap), 24/CU queued.
__global__ __launch_bounds__(256)
void fused_seis_kernel(const float* __restrict__ ms,   // (64, 9)
                       const float* __restrict__ rc,   // (32, 2)
                       const float* __restrict__ tab,  // (64, 64, 3, 614, 6)
                       float* __restrict__ out)        // (64, 32, 3, 512)
{
  __shared__ float y_s[NTI];
  __shared__ float m_s[NTI];

  const int tid = threadIdx.x;
  // XCD-aware bijective swizzle (T1): 6144 blocks, 8 XCDs -> 768 consecutive
  // work-ids per XCD = 256 pairs * 3 components = 8 whole models per XCD.
  const int wid  = (blockIdx.x & 7) * 768 + (blockIdx.x >> 3);
  const int pair = wid / 3;
  const int k    = wid - 3 * pair;
  const int mi   = pair >> 5;            // / N_RECV
  const int ri   = pair & (N_RECV - 1);

  // ---------------- uniform scalar setup ----------------
  const float hx  = ms[mi*9 + 0] - rc[ri*2 + 0];
  const float hy  = ms[mi*9 + 1] - rc[ri*2 + 1];
  const float tsh = ms[mi*9 + 2];
  float mt[6];
#pragma unroll
  for (int j = 0; j < 6; ++j) mt[j] = ms[mi*9 + 3 + j];

  const float dxf = (float)DX_D;
  const float uu = (hx + 1.0f) / dxf;
  const float vv = (hy + 1.0f) / dxf;
  int i0 = (int)floorf(uu); i0 = min(max(i0, 0), NXg - 2);
  int j0 = (int)floorf(vv); j0 = min(max(j0, 0), NYg - 2);
  const float fu = uu - (float)i0;
  const float fv = vv - (float)j0;
  const float w00 = (1.f - fu) * (1.f - fv);
  const float w10 = fu * (1.f - fv);
  const float w01 = (1.f - fu) * fv;
  const float w11 = fu * fv;

  const size_t cellf = (size_t)3 * NTI * 6;       // 11052 floats per (i,j) cell
  const size_t koff  = (size_t)k * NTI * 6;       // this component's slice (3684 floats, %4==0)
  const float4* c00 = (const float4*)(tab + (size_t)( i0      * NYg + j0    ) * cellf + koff);
  const float4* c10 = (const float4*)(tab + (size_t)((i0 + 1) * NYg + j0    ) * cellf + koff);
  const float4* c01 = (const float4*)(tab + (size_t)( i0      * NYg + j0 + 1) * cellf + koff);
  const float4* c11 = (const float4*)(tab + (size_t)((i0 + 1) * NYg + j0 + 1) * cellf + koff);

  // ---------------- phase A: y[t] = sum_c w_c * dot(mt, table_c[k,t,:]) -------------
  // Two adjacent t's = 12 contiguous floats = 3 aligned float4 per corner.
  for (int tp = tid; tp < NTI / 2; tp += 256) {
    const int o4 = tp * 3;
    const int t0 = 2 * tp;
    float d0a = 0.f, d0b = 0.f;
    {
      const float4 q0 = c00[o4], q1 = c00[o4+1], q2 = c00[o4+2];
      d0a += w00 * (mt[0]*q0.x + mt[1]*q0.y + mt[2]*q0.z + mt[3]*q0.w + mt[4]*q1.x + mt[5]*q1.y);
      d0b += w00 * (mt[0]*q1.z + mt[1]*q1.w + mt[2]*q2.x + mt[3]*q2.y + mt[4]*q2.z + mt[5]*q2.w);
    }
    {
      const float4 q0 = c10[o4], q1 = c10[o4+1], q2 = c10[o4+2];
      d0a += w10 * (mt[0]*q0.x + mt[1]*q0.y + mt[2]*q0.z + mt[3]*q0.w + mt[4]*q1.x + mt[5]*q1.y);
      d0b += w10 * (mt[0]*q1.z + mt[1]*q1.w + mt[2]*q2.x + mt[3]*q2.y + mt[4]*q2.z + mt[5]*q2.w);
    }
    {
      const float4 q0 = c01[o4], q1 = c01[o4+1], q2 = c01[o4+2];
      d0a += w01 * (mt[0]*q0.x + mt[1]*q0.y + mt[2]*q0.z + mt[3]*q0.w + mt[4]*q1.x + mt[5]*q1.y);
      d0b += w01 * (mt[0]*q1.z + mt[1]*q1.w + mt[2]*q2.x + mt[3]*q2.y + mt[4]*q2.z + mt[5]*q2.w);
    }
    {
      const float4 q0 = c11[o4], q1 = c11[o4+1], q2 = c11[o4+2];
      d0a += w11 * (mt[0]*q0.x + mt[1]*q0.y + mt[2]*q0.z + mt[3]*q0.w + mt[4]*q1.x + mt[5]*q1.y);
      d0b += w11 * (mt[0]*q1.z + mt[1]*q1.w + mt[2]*q2.x + mt[3]*q2.y + mt[4]*q2.z + mt[5]*q2.w);
    }
    y_s[t0]     = d0a;
    y_s[t0 + 1] = d0b;
  }
  __syncthreads();

  // ---------------- phase A2: rhs_i = 6*(y[i-1]-2y[i]+y[i+1])/H^2 into m_s[1..612] ----
  const float hh = (float)(H_INT_D * H_INT_D);
  for (int t = tid; t < NTI - 2; t += 256) {
    const int i = t + 1;
    m_s[i] = 6.0f * (y_s[i-1] - 2.0f * y_s[i] + y_s[i+1]) / hh;
  }
  __syncthreads();

  // ---------------- phase B0: boundary elimination (NAK rows) -----------------------
  // 6*m1 = rhs_1 ; 6*m612 = rhs_612 ; fold into neighbors' rhs (b_0 -= m1, b_609 -= m612).
  if (tid == 0) {
    const float m1 = m_s[1] * (1.0f / 6.0f);
    m_s[1]  = m1;
    m_s[2] -= m1;
  } else if (tid == 1) {
    const float m612 = m_s[612] * (1.0f / 6.0f);
    m_s[612]  = m612;
    m_s[611] -= m612;
  }
  __syncthreads();

  // ---------------- phase B1: parallel truncated-inverse solve ----------------------
  // Interior system: tridiag(1,4,1), n=610, b_j = m_s[2+j].
  // x_i = sum_{|d|<=W} Ks[|d|] b_{i+d}  -  image_left  -  image_right
  float xreg[3];
  int   nq = 0;
  for (int i = tid; i < NU; i += 256, ++nq) {
    const float* b = &m_s[2];
    float acc = 0.0f;
#pragma unroll
    for (int d = -W; d <= W; ++d) {
      const int j = i + d;
      if (j >= 0 && j < NU) acc += Ks[d < 0 ? -d : d] * b[j];
    }
    if (i <= W - 2) {                 // left image (enforces ghost x_{-1}=0)
      for (int j = 0; j <= W - 2 - i; ++j) acc -= Ks[i + j + 2] * b[j];
    }
    const int ip = (NU - 1) - i;
    if (ip <= W - 2) {                // right image (enforces ghost x_n=0)
      for (int jp = 0; jp <= W - 2 - ip; ++jp) acc -= Ks[ip + jp + 2] * b[(NU - 1) - jp];
    }
    xreg[nq] = acc;
  }
  __syncthreads();
  nq = 0;
  for (int i = tid; i < NU; i += 256, ++nq) m_s[2 + i] = xreg[nq];
  __syncthreads();
  if (tid == 0)      m_s[0]   = 2.0f * m_s[1]   - m_s[2];    // endpoints
  else if (tid == 1) m_s[613] = 2.0f * m_s[612] - m_s[611];
  __syncthreads();

  // ---------------- phase C: cubic sample at t_out - tshift ----------------
  const float Hf   = (float)H_INT_D;
  const float h26  = (float)(H_INT_D * H_INT_D / 6.0);
  const float tstep = (float)(20.0 / 511.0);
  float* outp = out + (((size_t)(mi * N_RECV + ri) * 3) + k) * NTO;
  for (int t = tid; t < NTO; t += 256) {
    const float tout = (float)t * tstep;
    const float tq   = tout - tsh;
    const float uq   = (tq + 2.0f) / Hf;
    int idx = (int)floorf(uq);
    idx = min(max(idx, 0), NTI - 2);
    const float a  = (float)(idx + 1) - uq;
    const float b  = uq - (float)idx;
    const float a3 = a*a*a - a;
    const float b3 = b*b*b - b;
    outp[t] = a * y_s[idx] + b * y_s[idx + 1]
            + (a3 * m_s[idx] + b3 * m_s[idx + 1]) * h26;
  }
}

extern "C" void kernel_launch(void* const* d_in, const int* in_sizes, int n_in,
                              void* d_out, int out_size, void* d_ws, size_t ws_size,
                              hipStream_t stream) {
  const float* ms  = (const float*)d_in[0];   // model_samples (64,9)
  const float* rc  = (const float*)d_in[1];   // receivers (32,2)
  const float* tab = (const float*)d_in[2];   // lookup_table (64,64,3,614,6)
  float* out = (float*)d_out;                 // (64,32,3,512) f32

  fused_seis_kernel<<<dim3(N_MODELS * N_RECV * 3), dim3(256), 0, stream>>>(ms, rc, tab, out);
}

// Round 12
// 260.760 us; speedup vs baseline: 1.2530x; 1.0152x over previous
//
#include <hip/hip_runtime.h>

// Problem constants (from the reference)
namespace {
constexpr int N_MODELS = 64;
constexpr int N_RECV   = 32;
constexpr int NXg = 64, NYg = 64;
constexpr int NTI = 614;            // N_T_INT
constexpr int NTO = 512;            // N_T
constexpr int NU  = NTI - 4;        // 610 interior unknowns (m_2..m_611)
constexpr int W   = 16;             // truncated-inverse window; r^17 ~ 2e-10
constexpr double H_INT_D = 24.0 / 613.0;
constexpr double DX_D    = 2.0 / 63.0;

// Ks[a] = (-1)^a * (2-sqrt(3))^a / (2*sqrt(3)) — signed inverse-kernel taps
__device__ __constant__ float Ks[W + 1] = {
   0.2886751345948129f,  -0.0773502691896258f,   0.0207257033081726f,
  -0.0055534135887359f,   0.0014880108762223f,  -0.0003987097583156f,
   0.0001068340364620f,  -0.0000286260504370f,   0.0000076703256763f,
  -0.0000020552580728f,   0.0000005507044461f,  -0.0000001475608686f,
   0.0000000395388899f,  -0.0000000105944428f,   0.0000000028387720f,
  -0.0000000007606466f,   0.0000000002038148f
};
}

// One SINGLE-WAVE block per (model, receiver, component). 64 threads.
// LDS: y[614] + m[614] = 4.9 KB. 24 blocks/CU -> ALL resident (one generation);
// __launch_bounds__(64,6) = 6 waves/SIMD so VGPR alloc can't break residency.
__global__ __launch_bounds__(64, 6)
void fused_seis_kernel(const float* __restrict__ ms,   // (64, 9)
                       const float* __restrict__ rc,   // (32, 2)
                       const float* __restrict__ tab,  // (64, 64, 3, 614, 6)
                       float* __restrict__ out)        // (64, 32, 3, 512)
{
  __shared__ float y_s[NTI];
  __shared__ float m_s[NTI];

  const int tid = threadIdx.x;
  // XCD-aware bijective swizzle (T1): 6144 blocks, 8 XCDs -> 768 consecutive
  // work-ids per XCD = 8 whole models per XCD (corner cells stay in one L2).
  const int wid  = (blockIdx.x & 7) * 768 + (blockIdx.x >> 3);
  const int pair = wid / 3;
  const int k    = wid - 3 * pair;
  const int mi   = pair >> 5;            // / N_RECV
  const int ri   = pair & (N_RECV - 1);

  // ---------------- uniform scalar setup ----------------
  const float hx  = ms[mi*9 + 0] - rc[ri*2 + 0];
  const float hy  = ms[mi*9 + 1] - rc[ri*2 + 1];
  const float tsh = ms[mi*9 + 2];
  float mt[6];
#pragma unroll
  for (int j = 0; j < 6; ++j) mt[j] = ms[mi*9 + 3 + j];

  const float dxf = (float)DX_D;
  const float uu = (hx + 1.0f) / dxf;
  const float vv = (hy + 1.0f) / dxf;
  int i0 = (int)floorf(uu); i0 = min(max(i0, 0), NXg - 2);
  int j0 = (int)floorf(vv); j0 = min(max(j0, 0), NYg - 2);
  const float fu = uu - (float)i0;
  const float fv = vv - (float)j0;
  const float w00 = (1.f - fu) * (1.f - fv);
  const float w10 = fu * (1.f - fv);
  const float w01 = (1.f - fu) * fv;
  const float w11 = fu * fv;

  const size_t cellf = (size_t)3 * NTI * 6;       // 11052 floats per (i,j) cell
  const size_t koff  = (size_t)k * NTI * 6;       // component slice (3684 floats, %4==0)
  const float4* c00 = (const float4*)(tab + (size_t)( i0      * NYg + j0    ) * cellf + koff);
  const float4* c10 = (const float4*)(tab + (size_t)((i0 + 1) * NYg + j0    ) * cellf + koff);
  const float4* c01 = (const float4*)(tab + (size_t)( i0      * NYg + j0 + 1) * cellf + koff);
  const float4* c11 = (const float4*)(tab + (size_t)((i0 + 1) * NYg + j0 + 1) * cellf + koff);

  // ---------------- phase A: y[t] = sum_c w_c * dot(mt, table_c[k,t,:]) -------------
  // Two adjacent t's = 12 contiguous floats = 3 aligned float4 per corner.
  // ~4.8 items/lane -> deep independent-load pipeline per wave.
  for (int tp = tid; tp < NTI / 2; tp += 64) {
    const int o4 = tp * 3;
    const int t0 = 2 * tp;
    float d0a = 0.f, d0b = 0.f;
    {
      const float4 q0 = c00[o4], q1 = c00[o4+1], q2 = c00[o4+2];
      d0a += w00 * (mt[0]*q0.x + mt[1]*q0.y + mt[2]*q0.z + mt[3]*q0.w + mt[4]*q1.x + mt[5]*q1.y);
      d0b += w00 * (mt[0]*q1.z + mt[1]*q1.w + mt[2]*q2.x + mt[3]*q2.y + mt[4]*q2.z + mt[5]*q2.w);
    }
    {
      const float4 q0 = c10[o4], q1 = c10[o4+1], q2 = c10[o4+2];
      d0a += w10 * (mt[0]*q0.x + mt[1]*q0.y + mt[2]*q0.z + mt[3]*q0.w + mt[4]*q1.x + mt[5]*q1.y);
      d0b += w10 * (mt[0]*q1.z + mt[1]*q1.w + mt[2]*q2.x + mt[3]*q2.y + mt[4]*q2.z + mt[5]*q2.w);
    }
    {
      const float4 q0 = c01[o4], q1 = c01[o4+1], q2 = c01[o4+2];
      d0a += w01 * (mt[0]*q0.x + mt[1]*q0.y + mt[2]*q0.z + mt[3]*q0.w + mt[4]*q1.x + mt[5]*q1.y);
      d0b += w01 * (mt[0]*q1.z + mt[1]*q1.w + mt[2]*q2.x + mt[3]*q2.y + mt[4]*q2.z + mt[5]*q2.w);
    }
    {
      const float4 q0 = c11[o4], q1 = c11[o4+1], q2 = c11[o4+2];
      d0a += w11 * (mt[0]*q0.x + mt[1]*q0.y + mt[2]*q0.z + mt[3]*q0.w + mt[4]*q1.x + mt[5]*q1.y);
      d0b += w11 * (mt[0]*q1.z + mt[1]*q1.w + mt[2]*q2.x + mt[3]*q2.y + mt[4]*q2.z + mt[5]*q2.w);
    }
    y_s[t0]     = d0a;
    y_s[t0 + 1] = d0b;
  }
  __syncthreads();   // single-wave block: compiles to a cheap waitcnt

  // ---------------- phase A2: rhs_i = 6*(y[i-1]-2y[i]+y[i+1])/H^2 into m_s[1..612] ----
  const float hh = (float)(H_INT_D * H_INT_D);
  for (int t = tid; t < NTI - 2; t += 64) {
    const int i = t + 1;
    m_s[i] = 6.0f * (y_s[i-1] - 2.0f * y_s[i] + y_s[i+1]) / hh;
  }
  __syncthreads();

  // ---------------- phase B0: boundary elimination (NAK rows) -----------------------
  // 6*m1 = rhs_1 ; 6*m612 = rhs_612 ; fold into neighbors' rhs.
  if (tid == 0) {
    const float m1 = m_s[1] * (1.0f / 6.0f);
    m_s[1]  = m1;
    m_s[2] -= m1;
  } else if (tid == 1) {
    const float m612 = m_s[612] * (1.0f / 6.0f);
    m_s[612]  = m612;
    m_s[611] -= m612;
  }
  __syncthreads();

  // ---------------- phase B1: parallel truncated-inverse solve ----------------------
  // Interior system: tridiag(1,4,1), n=610, b_j = m_s[2+j].
  // x_i = sum_{|d|<=W} Ks[|d|] b_{i+d}  -  image_left  -  image_right
  // Fixed 10-slot register buffer, fully unrolled (compile-time indices; rule #20).
  float xreg[10];
#pragma unroll
  for (int q = 0; q < 10; ++q) {
    const int i = tid + 64 * q;
    if (i < NU) {
      const float* b = &m_s[2];
      float acc = 0.0f;
#pragma unroll
      for (int d = -W; d <= W; ++d) {
        const int j = i + d;
        if (j >= 0 && j < NU) acc += Ks[d < 0 ? -d : d] * b[j];
      }
      if (i <= W - 2) {                 // left image (enforces ghost x_{-1}=0)
        for (int j = 0; j <= W - 2 - i; ++j) acc -= Ks[i + j + 2] * b[j];
      }
      const int ip = (NU - 1) - i;
      if (ip <= W - 2) {                // right image (enforces ghost x_n=0)
        for (int jp = 0; jp <= W - 2 - ip; ++jp) acc -= Ks[ip + jp + 2] * b[(NU - 1) - jp];
      }
      xreg[q] = acc;
    }
  }
  __syncthreads();
#pragma unroll
  for (int q = 0; q < 10; ++q) {
    const int i = tid + 64 * q;
    if (i < NU) m_s[2 + i] = xreg[q];
  }
  __syncthreads();
  if (tid == 0)      m_s[0]   = 2.0f * m_s[1]   - m_s[2];    // endpoints
  else if (tid == 1) m_s[613] = 2.0f * m_s[612] - m_s[611];
  __syncthreads();

  // ---------------- phase C: cubic sample at t_out - tshift ----------------
  const float Hf   = (float)H_INT_D;
  const float h26  = (float)(H_INT_D * H_INT_D / 6.0);
  const float tstep = (float)(20.0 / 511.0);
  float* outp = out + (((size_t)(mi * N_RECV + ri) * 3) + k) * NTO;
  for (int t = tid; t < NTO; t += 64) {
    const float tout = (float)t * tstep;
    const float tq   = tout - tsh;
    const float uq   = (tq + 2.0f) / Hf;
    int idx = (int)floorf(uq);
    idx = min(max(idx, 0), NTI - 2);
    const float a  = (float)(idx + 1) - uq;
    const float b  = uq - (float)idx;
    const float a3 = a*a*a - a;
    const float b3 = b*b*b - b;
    outp[t] = a * y_s[idx] + b * y_s[idx + 1]
            + (a3 * m_s[idx] + b3 * m_s[idx + 1]) * h26;
  }
}

extern "C" void kernel_launch(void* const* d_in, const int* in_sizes, int n_in,
                              void* d_out, int out_size, void* d_ws, size_t ws_size,
                              hipStream_t stream) {
  const float* ms  = (const float*)d_in[0];   // model_samples (64,9)
  const float* rc  = (const float*)d_in[1];   // receivers (32,2)
  const float* tab = (const float*)d_in[2];   // lookup_table (64,64,3,614,6)
  float* out = (float*)d_out;                 // (64,32,3,512) f32

  fused_seis_kernel<<<dim3(N_MODELS * N_RECV * 3), dim3(64), 0, stream>>>(ms, rc, tab, out);
}